// Round 1
// baseline (158.618 us; speedup 1.0000x reference)
//
#include <hip/hip_runtime.h>

// Problem constants (from reference): B=32, M=32, C=1024, R=28
#define Rr 28
#define Bb 32
#define Mm 32
#define Cc 1024

// ---------------------------------------------------------------------------
// Kernel 1: column sums of Masks.  colbuf[b,m,r] = sum_i Mk[b,m,i,r]
// 28672 outputs, one thread each, lane-coalesced (consecutive lanes -> consecutive r).
// Tiny: reads 3.2 MB, writes 114 KB.
// ---------------------------------------------------------------------------
#define NCOLS (Bb * Mm * Rr)   // 28672
#define COLBLKS (NCOLS / 256)  // 112

__global__ __launch_bounds__(256) void col_reduce(
    const float* __restrict__ Mk, float* __restrict__ colbuf) {
    int t = blockIdx.x * 256 + threadIdx.x;
    int bm = t / Rr;
    int r  = t - bm * Rr;
    const float* p = Mk + (size_t)bm * (Rr * Rr) + r;
    float s = 0.f;
#pragma unroll
    for (int i = 0; i < Rr; ++i) s += p[i * Rr];
    colbuf[t] = s;
}

// ---------------------------------------------------------------------------
// Kernel 2: FUSED row-reduction + batched tiny GEMM.
//   Each block owns (b, 64-channel tile).  Its F region is fully contiguous
//   (64*784 floats).  Phase 1: row sums 64ch x 28r -> LDS (no rowbuf in HBM).
//   Phase 2: S[b,m,c0+cl] = (1/784) * sum_r col_s[m][r] * row_s[cl][r].
// Grid = 32 * 16 = 512 blocks = 2 blocks/CU, 8 waves/CU.
// LDS padded stride 29 (odd): row_s read stride 29 across 64 lanes -> each
// bank hit exactly 2x = conflict-free; col_s reads are wave-uniform broadcast.
// ---------------------------------------------------------------------------
#define CT 64   // channels per block

__global__ __launch_bounds__(256) void fused_rowsum_gemm(
    const float* __restrict__ F, const float* __restrict__ colbuf,
    float* __restrict__ S) {
    __shared__ float row_s[CT * 29];   // 64 channels x 28 row-sums, padded
    __shared__ float col_s[Mm * 29];   // 32 masks   x 28 col-sums, padded

    const int b  = blockIdx.x >> 4;          // batch
    const int c0 = (blockIdx.x & 15) * CT;   // channel-tile base
    const int t  = threadIdx.x;

    // stage col[b]: 32*28 = 896 floats (L2-resident, 16 blocks share it)
    for (int idx = t; idx < Mm * Rr; idx += 256) {
        int m = idx / Rr, r = idx - m * Rr;
        col_s[m * 29 + r] = colbuf[(size_t)b * (Mm * Rr) + idx];
    }

    // Phase 1: row sums.  64ch * 28rows = 1792 rows, 7 per thread.
    // Each row is 28 contiguous floats = 7 float4 (112 B, 16B-aligned).
    const float* Fb = F + ((size_t)b * Cc + c0) * (Rr * Rr);
#pragma unroll
    for (int it = 0; it < 7; ++it) {
        int rr = t + it * 256;                 // 0..1791
        int ch = rr / Rr, r = rr - ch * Rr;
        const float4* p = (const float4*)(Fb + (size_t)ch * (Rr * Rr) + (size_t)r * Rr);
        float s = 0.f;
#pragma unroll
        for (int q = 0; q < 7; ++q) {
            float4 v = p[q];
            s += (v.x + v.y) + (v.z + v.w);
        }
        row_s[ch * 29 + r] = s;
    }
    __syncthreads();

    // Phase 2: tiny GEMM from LDS.
    const int cl = t & (CT - 1);   // lane-consecutive channel -> coalesced stores
    const int mq = t >> 6;         // 0..3, wave-uniform
    float rreg[Rr];
#pragma unroll
    for (int r = 0; r < Rr; ++r) rreg[r] = row_s[cl * 29 + r];

    const float inv = 1.0f / (Rr * Rr);
    for (int m = mq; m < Mm; m += 4) {
        float acc = 0.f;
#pragma unroll
        for (int r = 0; r < Rr; ++r)
            acc += col_s[m * 29 + r] * rreg[r];   // wave-uniform broadcast read
        S[((size_t)b * Mm + m) * Cc + c0 + cl] = acc * inv;
    }
}

extern "C" void kernel_launch(void* const* d_in, const int* in_sizes, int n_in,
                              void* d_out, int out_size, void* d_ws, size_t ws_size,
                              hipStream_t stream) {
    const float* F  = (const float*)d_in[0];   // (B, C, R, R) fp32
    const float* Mk = (const float*)d_in[1];   // (B, M, R, R) fp32
    float* S = (float*)d_out;                  // (B, M, C) fp32

    float* colbuf = (float*)d_ws;              // B*M*R floats = 114 KB

    col_reduce<<<COLBLKS, 256, 0, stream>>>(Mk, colbuf);
    fused_rowsum_gemm<<<Bb * 16, 256, 0, stream>>>(F, colbuf, S);
}

// Round 2
// 157.164 us; speedup vs baseline: 1.0093x; 1.0093x over previous
//
#include <hip/hip_runtime.h>

// Problem constants (from reference): B=32, M=32, C=1024, R=28
#define Rr 28
#define Bb 32
#define Mm 32
#define Cc 1024

// ---------------------------------------------------------------------------
// Kernel 1: column sums of Masks.  colbuf[b,m,r] = sum_i Mk[b,m,i,r]
// 28672 outputs, one thread each, lane-coalesced. Reads 3.2 MB, writes 114 KB.
// ---------------------------------------------------------------------------
#define NCOLS (Bb * Mm * Rr)   // 28672
#define COLBLKS (NCOLS / 256)  // 112

__global__ __launch_bounds__(256) void col_reduce(
    const float* __restrict__ Mk, float* __restrict__ colbuf) {
    int t = blockIdx.x * 256 + threadIdx.x;
    int bm = t / Rr;
    int r  = t - bm * Rr;
    const float* p = Mk + (size_t)bm * (Rr * Rr) + r;
    float s = 0.f;
#pragma unroll
    for (int i = 0; i < Rr; ++i) s += p[i * Rr];
    colbuf[t] = s;
}

// ---------------------------------------------------------------------------
// Kernel 2: FUSED row-reduction + batched tiny GEMM, fully-coalesced F reads.
//
// Block = (b, 64-channel tile); its F region is contiguous: 64*784 floats
// = 12544 float4 = 7 tiles x (7 iters x 256 threads).
//
// Phase 1 per tile k (software-pipelined):
//   1a: thread t loads float4 g = k*1792 + q*256 + t  (lane-consecutive ->
//       each wave instr reads 1 KiB contiguous), horizontal-sums to s[q].
//   issue tile k+1's 7 loads (regs) BEFORE the barrier -> HBM latency hides
//       under the LDS reduce of tile k.
//   1b: part_s[t*7+j] 7:1 reduce -> row_s[ch*29+r].  Stride-7 LDS reads are
//       bank-conflict-free (7 coprime 32, 2 lanes/bank = free).
// Phase 2: tiny GEMM  S[b,m,c0+cl] = (1/784) * sum_r col_s[m][r]*row_s[cl][r].
//
// LDS: part 7168 + row 7424 + col 3712 = 18.3 KB.  Grid 512 = 2 blocks/CU,
// 8 waves/CU; 7 loads in flight/wave covers ~900cy HBM latency.
// ---------------------------------------------------------------------------
#define CT 64   // channels per block (CT*28 rows must divide by 256 -> CT=64)

__global__ __launch_bounds__(256) void fused_rowsum_gemm(
    const float* __restrict__ F, const float* __restrict__ colbuf,
    float* __restrict__ S) {
    __shared__ float part_s[7 * 256];     // per-float4 partials for one tile
    __shared__ float row_s[CT * 29];      // 64 ch x 28 row-sums, padded
    __shared__ float col_s[Mm * 29];      // 32 masks x 28 col-sums, padded

    const int b  = blockIdx.x >> 4;          // batch
    const int c0 = (blockIdx.x & 15) * CT;   // channel-tile base
    const int t  = threadIdx.x;

    // stage col[b]: 32*28 = 896 floats (L2-resident; 16 blocks share it)
    for (int idx = t; idx < Mm * Rr; idx += 256) {
        int m = idx / Rr, r = idx - m * Rr;
        col_s[m * 29 + r] = colbuf[(size_t)b * (Mm * Rr) + idx];
    }

    const float4* Fb4 = (const float4*)(F + ((size_t)b * Cc + c0) * (Rr * Rr));

    // prefetch tile 0
    float4 v[7];
#pragma unroll
    for (int q = 0; q < 7; ++q) v[q] = Fb4[q * 256 + t];

#pragma unroll
    for (int k = 0; k < 7; ++k) {
        // horizontal sums of current tile (frees v[] for the next prefetch)
        float s[7];
#pragma unroll
        for (int q = 0; q < 7; ++q)
            s[q] = (v[q].x + v[q].y) + (v[q].z + v[q].w);

        // issue next tile's loads early: in flight across barrier + reduce
        if (k < 6) {
            const float4* p = Fb4 + (k + 1) * 1792;
#pragma unroll
            for (int q = 0; q < 7; ++q) v[q] = p[q * 256 + t];
        }

        // 1a: partials -> LDS (consecutive banks, conflict-free)
#pragma unroll
        for (int q = 0; q < 7; ++q) part_s[q * 256 + t] = s[q];
        __syncthreads();

        // 1b: 7:1 reduce -> row_s.  This tile covers rows [k*256,(k+1)*256).
        int rg = k * 256 + t;
        int ch = rg / Rr, r = rg - ch * Rr;
        float rs = 0.f;
#pragma unroll
        for (int j = 0; j < 7; ++j) rs += part_s[t * 7 + j];
        row_s[ch * 29 + r] = rs;
        __syncthreads();   // WAR: part_s reused next tile
    }

    // Phase 2: tiny GEMM from LDS.
    const int cl = t & (CT - 1);   // lane-consecutive channel -> coalesced stores
    const int mq = t >> 6;         // 0..3, wave-uniform
    float rreg[Rr];
#pragma unroll
    for (int r = 0; r < Rr; ++r) rreg[r] = row_s[cl * 29 + r];

    const float inv = 1.0f / (Rr * Rr);
    for (int m = mq; m < Mm; m += 4) {
        float acc = 0.f;
#pragma unroll
        for (int r = 0; r < Rr; ++r)
            acc += col_s[m * 29 + r] * rreg[r];   // wave-uniform broadcast read
        S[((size_t)b * Mm + m) * Cc + c0 + cl] = acc * inv;
    }
}

extern "C" void kernel_launch(void* const* d_in, const int* in_sizes, int n_in,
                              void* d_out, int out_size, void* d_ws, size_t ws_size,
                              hipStream_t stream) {
    const float* F  = (const float*)d_in[0];   // (B, C, R, R) fp32
    const float* Mk = (const float*)d_in[1];   // (B, M, R, R) fp32
    float* S = (float*)d_out;                  // (B, M, C) fp32

    float* colbuf = (float*)d_ws;              // B*M*R floats = 114 KB

    col_reduce<<<COLBLKS, 256, 0, stream>>>(Mk, colbuf);
    fused_rowsum_gemm<<<Bb * 16, 256, 0, stream>>>(F, colbuf, S);
}

// Round 4
// 154.503 us; speedup vs baseline: 1.0266x; 1.0172x over previous
//
#include <hip/hip_runtime.h>

// Problem constants (from reference): B=32, M=32, C=1024, R=28
#define Rr 28
#define Bb 32
#define Mm 32
#define Cc 1024
#define CT 64   // channels per block

// ---------------------------------------------------------------------------
// Single fused kernel: per-block col-sums (from Masks) + row-sums (from F)
// + tiny GEMM.  Grid = 512 blocks = (32 batches x 16 channel-tiles).
//
// XCD-aware mapping: all 16 blocks of a batch share bid%8 (= XCD under the
// round-robin heuristic), so each batch's 98 KB mask region is HBM-fetched
// once and L2-served to the other 15 blocks.  Perf heuristic only.
//
// Phase 0: col_s[m][r] = sum_i Mk[b,m,i,r].  224 threads, one (mask, float4
//          segment) each: 28 float4 loads, register-accumulated.  Waves 0-3's
//          idle lanes fall through to phase 1's horizontal sums (overlap).
// Phase 1: row sums of the 64-channel F tile, 7 software-pipelined subtiles:
//          coalesced float4 loads -> horizontal sums -> LDS transpose
//          (part_s) -> 7:1 reduce -> row_s.  Next subtile's loads issued
//          before the barrier so HBM latency hides under the LDS reduce.
// Phase 2: S[b,m,c0+cl] = (1/784) * sum_r col_s[m][r] * row_s[cl][r].
//
// LDS 18.3 KB; stride-29 padding keeps every LDS access <=2 lanes/bank (free).
// ---------------------------------------------------------------------------
__global__ __launch_bounds__(256) void fused_all(
    const float* __restrict__ F, const float* __restrict__ Mk,
    float* __restrict__ S) {
    __shared__ float part_s[7 * 256];     // per-float4 partials for one subtile
    __shared__ float row_s[CT * 29];      // 64 ch x 28 row-sums, padded
    __shared__ float col_s[Mm * 29];      // 32 masks x 28 col-sums, padded

    const int bid = blockIdx.x;
    const int xcd = bid & 7;
    const int kk  = bid >> 3;             // 0..63
    const int b   = xcd * 4 + (kk >> 4);  // batch: all 16 tiles share bid%8
    const int c0  = (kk & 15) * CT;       // channel-tile base
    const int t   = threadIdx.x;

    const float4* Fb4 = (const float4*)(F + ((size_t)b * Cc + c0) * (Rr * Rr));

    // prefetch F subtile 0 first: its ~900cy HBM latency hides under phase 0
    float4 v[7];
#pragma unroll
    for (int q = 0; q < 7; ++q) v[q] = Fb4[q * 256 + t];

    // Phase 0: col sums.  thread -> (mask m, 4-column segment seg).
    if (t < Mm * 7) {
        const int m = t / 7, seg = t - m * 7;
        const float4* Mp = (const float4*)(Mk + ((size_t)b * Mm + m) * (Rr * Rr)) + seg;
        float4 a = {0.f, 0.f, 0.f, 0.f};
#pragma unroll
        for (int i = 0; i < Rr; ++i) {
            float4 w = Mp[i * 7];         // row i, cols seg*4..seg*4+3
            a.x += w.x; a.y += w.y; a.z += w.z; a.w += w.w;
        }
        const int r0 = seg * 4;
        col_s[m * 29 + r0 + 0] = a.x;
        col_s[m * 29 + r0 + 1] = a.y;
        col_s[m * 29 + r0 + 2] = a.z;
        col_s[m * 29 + r0 + 3] = a.w;
    }

    // Phase 1: row sums, 7 pipelined subtiles of 1792 float4.
#pragma unroll
    for (int k = 0; k < 7; ++k) {
        float s[7];
#pragma unroll
        for (int q = 0; q < 7; ++q)
            s[q] = (v[q].x + v[q].y) + (v[q].z + v[q].w);

        if (k < 6) {                      // issue next subtile's loads early
            const float4* p = Fb4 + (k + 1) * 1792;
#pragma unroll
            for (int q = 0; q < 7; ++q) v[q] = p[q * 256 + t];
        }

#pragma unroll
        for (int q = 0; q < 7; ++q) part_s[q * 256 + t] = s[q];
        __syncthreads();                  // also orders col_s before phase 2

        // rows [k*256, (k+1)*256): row k*256+t = float4s {t*7+j} of this subtile
        int rg = k * 256 + t;
        int ch = rg / Rr, r = rg - ch * Rr;
        float rs = 0.f;
#pragma unroll
        for (int j = 0; j < 7; ++j) rs += part_s[t * 7 + j];
        row_s[ch * 29 + r] = rs;
        __syncthreads();                  // WAR: part_s reused next subtile
    }

    // Phase 2: tiny GEMM from LDS.
    const int cl = t & (CT - 1);          // lane-consecutive channel -> coalesced stores
    const int mq = t >> 6;                // 0..3, wave-uniform
    float rreg[Rr];
#pragma unroll
    for (int r = 0; r < Rr; ++r) rreg[r] = row_s[cl * 29 + r];

    const float inv = 1.0f / (Rr * Rr);
    for (int m = mq; m < Mm; m += 4) {
        float acc = 0.f;
#pragma unroll
        for (int r = 0; r < Rr; ++r)
            acc += col_s[m * 29 + r] * rreg[r];   // wave-uniform broadcast read
        S[((size_t)b * Mm + m) * Cc + c0 + cl] = acc * inv;
    }
}

extern "C" void kernel_launch(void* const* d_in, const int* in_sizes, int n_in,
                              void* d_out, int out_size, void* d_ws, size_t ws_size,
                              hipStream_t stream) {
    const float* F  = (const float*)d_in[0];   // (B, C, R, R) fp32
    const float* Mk = (const float*)d_in[1];   // (B, M, R, R) fp32
    float* S = (float*)d_out;                  // (B, M, C) fp32

    fused_all<<<Bb * 16, 256, 0, stream>>>(F, Mk, S);
}

// Round 5
// 154.101 us; speedup vs baseline: 1.0293x; 1.0026x over previous
//
#include <hip/hip_runtime.h>

// Problem constants (from reference): B=32, M=32, C=1024, R=28
#define Rr 28
#define Bb 32
#define Mm 32
#define Cc 1024
#define CT 64   // channels per block

// ---------------------------------------------------------------------------
// Single fused kernel: per-block col-sums (Masks) + row-sums (F) + tiny GEMM.
// Grid = 512 blocks = (32 batches x 16 channel-tiles), 2 blocks/CU.
//
// XCD-aware mapping: all 16 blocks of a batch share bid%8 (= XCD under the
// round-robin heuristic) -> each batch's 98 KB mask region is HBM-fetched
// once and L2-served to the other 15 blocks.  Perf heuristic only.
//
// Phase 0: col_s[m][r] = sum_i Mk[b,m,i,r] (224 threads, float4 segments).
// Phase 1: row sums of the 64-ch F tile, 7 subtiles, 2-DEEP double-buffered
//          prefetch: tile k+1's 7x1KB coalesced loads are issued BEFORE the
//          horizontal sums of tile k, so each load has a full iteration
//          (~5 us of LDS reduce + HS work) of latency cover and the HBM
//          request stream never drains (compiler emits vmcnt(7)-style
//          counted waits, not vmcnt(0)).
// Phase 2: S[b,m,c0+cl] = (1/784) * sum_r col_s[m][r] * row_s[cl][r].
//
// LDS 18.3 KB; stride-29 padding keeps every LDS access <=2 lanes/bank (free).
// Buffer alternation is macro-unrolled so all register indexing is static
// (runtime-indexed ext_vector arrays would spill to scratch).
// ---------------------------------------------------------------------------
__global__ __launch_bounds__(256) void fused_all(
    const float* __restrict__ F, const float* __restrict__ Mk,
    float* __restrict__ S) {
    __shared__ float part_s[7 * 256];     // per-float4 partials for one subtile
    __shared__ float row_s[CT * 29];      // 64 ch x 28 row-sums, padded
    __shared__ float col_s[Mm * 29];      // 32 masks x 28 col-sums, padded

    const int bid = blockIdx.x;
    const int xcd = bid & 7;
    const int kk  = bid >> 3;             // 0..63
    const int b   = xcd * 4 + (kk >> 4);  // batch: all 16 tiles share bid%8
    const int c0  = (kk & 15) * CT;       // channel-tile base
    const int t   = threadIdx.x;

    const float4* Fb4 = (const float4*)(F + ((size_t)b * Cc + c0) * (Rr * Rr));

    // prefetch F subtile 0; its HBM latency hides under phase 0
    float4 va[7], vb[7];
#pragma unroll
    for (int q = 0; q < 7; ++q) va[q] = Fb4[q * 256 + t];

    // Phase 0: col sums.  thread -> (mask m, 4-column segment seg).
    if (t < Mm * 7) {
        const int m = t / 7, seg = t - m * 7;
        const float4* Mp = (const float4*)(Mk + ((size_t)b * Mm + m) * (Rr * Rr)) + seg;
        float4 a = {0.f, 0.f, 0.f, 0.f};
#pragma unroll
        for (int i = 0; i < Rr; ++i) {
            float4 w = Mp[i * 7];         // row i, cols seg*4..seg*4+3
            a.x += w.x; a.y += w.y; a.z += w.z; a.w += w.w;
        }
        const int r0 = seg * 4;
        col_s[m * 29 + r0 + 0] = a.x;
        col_s[m * 29 + r0 + 1] = a.y;
        col_s[m * 29 + r0 + 2] = a.z;
        col_s[m * 29 + r0 + 3] = a.w;
    }

    // Phase 1 body: issue tile k+1 into NXT, then consume CUR (tile k).
    // The waitcnt for CUR's use leaves NXT's 7 loads outstanding.
#define BODY(k, CUR, NXT)                                                  \
    {                                                                      \
        if ((k) < 6) {                                                     \
            const float4* p = Fb4 + ((k) + 1) * 1792;                      \
            _Pragma("unroll")                                              \
            for (int q = 0; q < 7; ++q) NXT[q] = p[q * 256 + t];           \
        }                                                                  \
        float s[7];                                                        \
        _Pragma("unroll")                                                  \
        for (int q = 0; q < 7; ++q)                                        \
            s[q] = (CUR[q].x + CUR[q].y) + (CUR[q].z + CUR[q].w);          \
        _Pragma("unroll")                                                  \
        for (int q = 0; q < 7; ++q) part_s[q * 256 + t] = s[q];            \
        __syncthreads();                                                   \
        int rg = (k) * 256 + t;                                            \
        int ch = rg / Rr, r = rg - ch * Rr;                                \
        float rs = 0.f;                                                    \
        _Pragma("unroll")                                                  \
        for (int j = 0; j < 7; ++j) rs += part_s[t * 7 + j];               \
        row_s[ch * 29 + r] = rs;                                           \
        __syncthreads(); /* WAR: part_s reused next subtile */             \
    }

    BODY(0, va, vb)
    BODY(1, vb, va)
    BODY(2, va, vb)
    BODY(3, vb, va)
    BODY(4, va, vb)
    BODY(5, vb, va)
    BODY(6, va, vb)
#undef BODY

    // Phase 2: tiny GEMM from LDS.
    const int cl = t & (CT - 1);          // lane-consecutive channel -> coalesced stores
    const int mq = t >> 6;                // 0..3, wave-uniform
    float rreg[Rr];
#pragma unroll
    for (int r = 0; r < Rr; ++r) rreg[r] = row_s[cl * 29 + r];

    const float inv = 1.0f / (Rr * Rr);
    for (int m = mq; m < Mm; m += 4) {
        float acc = 0.f;
#pragma unroll
        for (int r = 0; r < Rr; ++r)
            acc += col_s[m * 29 + r] * rreg[r];   // wave-uniform broadcast read
        S[((size_t)b * Mm + m) * Cc + c0 + cl] = acc * inv;
    }
}

extern "C" void kernel_launch(void* const* d_in, const int* in_sizes, int n_in,
                              void* d_out, int out_size, void* d_ws, size_t ws_size,
                              hipStream_t stream) {
    const float* F  = (const float*)d_in[0];   // (B, C, R, R) fp32
    const float* Mk = (const float*)d_in[1];   // (B, M, R, R) fp32
    float* S = (float*)d_out;                  // (B, M, C) fp32

    fused_all<<<Bb * 16, 256, 0, stream>>>(F, Mk, S);
}